// Round 3
// baseline (681.852 us; speedup 1.0000x reference)
//
#include <hip/hip_runtime.h>
#include <math.h>

#define SEQ  2048
#define CDIM 2048
#define NH   16
#define DH   128
#define HDIM 2048   // NH * DH

typedef __attribute__((ext_vector_type(8))) short  bf16x8;  // 8 bf16 = 4 VGPRs
typedef __attribute__((ext_vector_type(4))) float  f32x4;   // MFMA acc
typedef unsigned short ushort_t;

__device__ __forceinline__ unsigned short f2bf(float f) {   // RNE float->bf16
  unsigned u = __float_as_uint(f);
  u = (u + 0x7fffu + ((u >> 16) & 1u)) >> 16;
  return (unsigned short)u;
}
__device__ __forceinline__ float b2f(unsigned short s) {
  return __uint_as_float((unsigned)s << 16);
}

// async global->LDS, 16B per lane. LDS dest is wave-uniform base + lane*16.
__device__ __forceinline__ void async_ld16(const ushort_t* g, ushort_t* l) {
  __builtin_amdgcn_global_load_lds((const __attribute__((address_space(1))) unsigned int*)g,
                                   (__attribute__((address_space(3))) unsigned int*)l,
                                   16, 0, 0);
}

__device__ __forceinline__ f32x4 mfma16(bf16x8 a, bf16x8 b, f32x4 c) {
  return __builtin_amdgcn_mfma_f32_16x16x32_bf16(a, b, c, 0, 0, 0);
}

// ---------------------------------------------------------------------------
// fp32 -> bf16 pack, 8 elems/thread
// ---------------------------------------------------------------------------
__global__ __launch_bounds__(256) void to_bf16(const float* __restrict__ src,
                                               ushort_t* __restrict__ dst, int n8) {
  int i = blockIdx.x * 256 + threadIdx.x;
  if (i >= n8) return;
  const float4* s = (const float4*)src;
  float4 f0 = s[i * 2], f1 = s[i * 2 + 1];
  bf16x8 o;
  o[0] = (short)f2bf(f0.x); o[1] = (short)f2bf(f0.y);
  o[2] = (short)f2bf(f0.z); o[3] = (short)f2bf(f0.w);
  o[4] = (short)f2bf(f1.x); o[5] = (short)f2bf(f1.y);
  o[6] = (short)f2bf(f1.z); o[7] = (short)f2bf(f1.w);
  *(bf16x8*)&dst[i * 8] = o;
}

// ---------------------------------------------------------------------------
// QKV GEMM (NT) + fused epilogue: rmsnorm + rope (z<2) / v-mix + V-transpose
// (z==2). C-tile = 128 t-rows x 1 head (n-tile 128 == DH). Col remap puts
// rope pairs (c, c+64) in the same lane: col(ni) = (ni&1)*16+wn*32+(ni>>1)*64.
// ---------------------------------------------------------------------------
__global__ __launch_bounds__(256, 3) void gemm_qkv(const ushort_t* __restrict__ A,
                                                   const ushort_t* __restrict__ B,
                                                   ushort_t* __restrict__ qkvb,
                                                   ushort_t* __restrict__ vbT,
                                                   const float* __restrict__ ve,
                                                   const float* __restrict__ lambdas) {
  constexpr int K = CDIM;
  __shared__ __align__(16) ushort_t As[128 * 32];
  __shared__ __align__(16) ushort_t Bs[128 * 32];
  __shared__ float red[4][4][4][4];   // [wave][mi][g][r]
  const int z = blockIdx.z;
  const ushort_t* Bp = B + (long)z * HDIM * CDIM;
  const int m0 = blockIdx.y * 128, n0 = blockIdx.x * 128;
  const int tid = threadIdx.x, lane = tid & 63, wave = tid >> 6;
  const int wm = wave >> 1, wn = wave & 1;
  const int g = lane >> 4, l15 = lane & 15;
  const int srow = tid >> 2, scc = tid & 3;

  f32x4 acc[4][4];
#pragma unroll
  for (int i = 0; i < 4; ++i)
#pragma unroll
    for (int j = 0; j < 4; ++j) acc[i][j] = (f32x4)0.0f;

  for (int k0 = 0; k0 < K; k0 += 32) {
    __syncthreads();
    {
      int r0 = srow, r1 = srow + 64;
      int c0 = scc ^ ((r0 >> 1) & 3), c1 = scc ^ ((r1 >> 1) & 3);
      async_ld16(&A [(long)(m0 + r0) * K + k0 + c0 * 8], &As[wave * 512]);
      async_ld16(&A [(long)(m0 + r1) * K + k0 + c1 * 8], &As[2048 + wave * 512]);
      async_ld16(&Bp[(long)(n0 + r0) * K + k0 + c0 * 8], &Bs[wave * 512]);
      async_ld16(&Bp[(long)(n0 + r1) * K + k0 + c1 * 8], &Bs[2048 + wave * 512]);
    }
    __syncthreads();

    bf16x8 af[4], bfr[4];
#pragma unroll
    for (int mi = 0; mi < 4; ++mi) {
      int row = wm * 64 + mi * 16 + l15;
      int cc = g ^ ((row >> 1) & 3);
      af[mi] = *(const bf16x8*)&As[row * 32 + cc * 8];
    }
#pragma unroll
    for (int ni = 0; ni < 4; ++ni) {
      int rowm = (ni & 1) * 16 + wn * 32 + (ni >> 1) * 64 + l15;   // col remap
      int cc = g ^ ((rowm >> 1) & 3);
      bfr[ni] = *(const bf16x8*)&Bs[rowm * 32 + cc * 8];
    }
#pragma unroll
    for (int mi = 0; mi < 4; ++mi)
#pragma unroll
      for (int ni = 0; ni < 4; ++ni)
        acc[mi][ni] = mfma16(af[mi], bfr[ni], acc[mi][ni]);
  }

  // ---- fused epilogue ----
  // rowsumsq over the 128 head-dims: in-lane over ni, shfl over l15, LDS over wn
  {
    float part[4][4];
#pragma unroll
    for (int mi = 0; mi < 4; ++mi)
#pragma unroll
      for (int r = 0; r < 4; ++r) {
        float s = 0.f;
#pragma unroll
        for (int ni = 0; ni < 4; ++ni) { float v = acc[mi][ni][r]; s += v * v; }
        part[mi][r] = s;
      }
#pragma unroll
    for (int mask = 1; mask < 16; mask <<= 1)
#pragma unroll
      for (int mi = 0; mi < 4; ++mi)
#pragma unroll
        for (int r = 0; r < 4; ++r)
          part[mi][r] += __shfl_xor(part[mi][r], mask, 64);
    __syncthreads();
    if (l15 == 0)
#pragma unroll
      for (int mi = 0; mi < 4; ++mi)
#pragma unroll
        for (int r = 0; r < 4; ++r) red[wave][mi][g][r] = part[mi][r];
    __syncthreads();
  }
  float scl[4][4];
#pragma unroll
  for (int mi = 0; mi < 4; ++mi)
#pragma unroll
    for (int r = 0; r < 4; ++r)
      scl[mi][r] = rsqrtf((red[wm * 2][mi][g][r] + red[wm * 2 + 1][mi][g][r]) *
                              (1.0f / 128.0f) + 1e-6f);

  if (z < 2) {
    ushort_t* dst = qkvb + (long)z * SEQ * HDIM;
#pragma unroll
    for (int ni2 = 0; ni2 < 2; ++ni2) {
      int c = ni2 * 16 + wn * 32 + l15;   // 0..63
      float freq = (c < 32) ? powf(9.765625e-4f, (float)c * (1.0f / 31.0f)) : 0.0f;
#pragma unroll
      for (int mi = 0; mi < 4; ++mi)
#pragma unroll
        for (int r = 0; r < 4; ++r) {
          int tt = m0 + wm * 64 + mi * 16 + g * 4 + r;
          float th = (float)tt * freq;
          float co = cosf(th), si = sinf(th);
          float x1 = acc[mi][ni2][r] * scl[mi][r];
          float x2 = acc[mi][ni2 + 2][r] * scl[mi][r];
          dst[(long)tt * HDIM + n0 + c]      = f2bf(x1 * co + x2 * si);
          dst[(long)tt * HDIM + n0 + c + 64] = f2bf(-x1 * si + x2 * co);
        }
    }
  } else {
    float l0 = lambdas[0], l1 = lambdas[1];
    ushort_t* dst = qkvb + 2L * SEQ * HDIM;
#pragma unroll
    for (int mi = 0; mi < 4; ++mi)
#pragma unroll
      for (int ni = 0; ni < 4; ++ni) {
        int c = (ni & 1) * 16 + wn * 32 + (ni >> 1) * 64 + l15;
        int t0q = m0 + wm * 64 + mi * 16 + g * 4;
        unsigned short pk[4];
#pragma unroll
        for (int r = 0; r < 4; ++r) {
          int tt = t0q + r;
          float vv = l0 * acc[mi][ni][r] * scl[mi][r] + l1 * ve[(long)tt * HDIM + n0 + c];
          unsigned short b = f2bf(vv);
          dst[(long)tt * HDIM + n0 + c] = b;
          pk[r] = b;
        }
        *(uint2*)&vbT[(long)(n0 + c) * SEQ + t0q] =
            make_uint2((unsigned)pk[0] | ((unsigned)pk[1] << 16),
                       (unsigned)pk[2] | ((unsigned)pk[3] << 16));
      }
  }
}

// ---------------------------------------------------------------------------
// MFMA flash attention, v2.
// Block = 256 thr (4 waves x 16 q-rows), processes paired q-tiles (x, 31-x)
// sequentially: constant 33 key-tile iterations (load-balanced).
// K/V double-buffered in LDS via global_load_lds; prefetch for iter j+1 is
// issued right after the barrier of iter j (the compiler's vmcnt(0)-before-
// s_barrier then waits on loads issued a full compute phase earlier).
// No online max: rms-normed q,k bound scores to |s|<=15.36, exp<=4.7e6 (fp32-safe).
// ---------------------------------------------------------------------------
__global__ __launch_bounds__(256) void flash_mfma(const ushort_t* __restrict__ qkvb,
                                                  const ushort_t* __restrict__ vbT,
                                                  ushort_t* __restrict__ yb) {
  __shared__ __align__(16) ushort_t Ks[2][64 * 128];
  __shared__ __align__(16) ushort_t Vt[2][128 * 64];
  __shared__ __align__(16) ushort_t Ps[64 * 72];
  const int xp = blockIdx.x, h = blockIdx.y;
  const int tid = threadIdx.x, lane = tid & 63, wave = tid >> 6;
  const int g = lane >> 4, l15 = lane & 15;
  const ushort_t* Kg = qkvb + (long)SEQ * HDIM + (long)h * DH;
  const ushort_t* Vg = vbT + (long)h * DH * SEQ;
  const int tA = xp, tB = 31 - xp;
  const int nA = xp + 1;           // key-tiles in part A; total = nA + (32-xp) = 33

  auto stage = [&](int buf, int s0) {
#pragma unroll
    for (int i = 0; i < 4; ++i) {
      int idx = i * 256 + tid;
      int rk = idx >> 4, ck = (idx & 15) ^ (rk & 7);
      async_ld16(&Kg[(long)(s0 + rk) * HDIM + ck * 8], &Ks[buf][i * 2048 + wave * 512]);
      int rv = idx >> 3, cv = (idx & 7) ^ (rv & 7);
      async_ld16(&Vg[(long)rv * SEQ + s0 + cv * 8], &Vt[buf][i * 2048 + wave * 512]);
    }
  };

  bf16x8 qf[4];
  auto loadQ = [&](int qt) {
#pragma unroll
    for (int ks = 0; ks < 4; ++ks)
      qf[ks] = *(const bf16x8*)
          &qkvb[(long)(qt * 64 + wave * 16 + l15) * HDIM + h * DH + ks * 32 + g * 8];
  };

  f32x4 oacc[8];
  float lrow = 0.f;
#pragma unroll
  for (int dt = 0; dt < 8; ++dt) oacc[dt] = (f32x4)0.0f;

  auto writeO = [&](int qt) {
    float linv[4];
#pragma unroll
    for (int r = 0; r < 4; ++r) linv[r] = 1.0f / __shfl(lrow, g * 4 + r, 64);
#pragma unroll
    for (int dt = 0; dt < 8; ++dt) {
      int row = qt * 64 + wave * 16 + g * 4;
      int col = h * DH + dt * 16 + l15;
#pragma unroll
      for (int r = 0; r < 4; ++r)
        yb[(long)(row + r) * HDIM + col] = f2bf(oacc[dt][r] * linv[r]);
    }
  };

  loadQ(tA);
  stage(0, 0);

  for (int j = 0; j < 33; ++j) {
    __syncthreads();                       // drains buf[j&1] loads (vmcnt 0 + barrier)
    int part = (j >= nA);
    int qt = part ? tB : tA;
    int s0 = (part ? (j - nA) : j) * 64;
    if (j == nA) {                         // part boundary: flush part A
      writeO(tA);
#pragma unroll
      for (int dt = 0; dt < 8; ++dt) oacc[dt] = (f32x4)0.0f;
      lrow = 0.f;
      loadQ(tB);
    }
    if (j + 1 < 33) {                      // prefetch next tile into other buffer
      int p2 = (j + 1 >= nA);
      int s2 = ((j + 1) - (p2 ? nA : 0)) * 64;
      stage((j + 1) & 1, s2);
    }
    const ushort_t* Kc = Ks[j & 1];
    const ushort_t* Vc = Vt[j & 1];

    // S^T = K·Q^T : C-layout lane: q = l15 (col), key = g*4+reg (row)
    f32x4 st[4];
#pragma unroll
    for (int mt = 0; mt < 4; ++mt) st[mt] = (f32x4)0.0f;
#pragma unroll
    for (int ks = 0; ks < 4; ++ks)
#pragma unroll
      for (int mt = 0; mt < 4; ++mt) {
        int row = mt * 16 + l15;
        bf16x8 a = *(const bf16x8*)&Kc[row * 128 + (((ks * 4 + g) ^ (row & 7)) * 8)];
        st[mt] = mfma16(a, qf[ks], st[mt]);
      }

    // P = exp(0.12*S) (masked -> 0), write to wave-private Ps, accumulate l
    const int qg = qt * 64 + wave * 16 + l15;
    const bool diag = (s0 == qt * 64);
    float psum = 0.f;
#pragma unroll
    for (int mt = 0; mt < 4; ++mt) {
      unsigned short pb[4];
#pragma unroll
      for (int r = 0; r < 4; ++r) {
        float e = (diag && (s0 + mt * 16 + g * 4 + r > qg))
                      ? 0.0f : __expf(st[mt][r] * 0.12f);
        unsigned short b = f2bf(e);
        pb[r] = b;
        psum += b2f(b);                   // l consistent with bf16-rounded P
      }
      *(uint2*)&Ps[(wave * 16 + l15) * 72 + mt * 16 + g * 4] =
          make_uint2((unsigned)pb[0] | ((unsigned)pb[1] << 16),
                     (unsigned)pb[2] | ((unsigned)pb[3] << 16));
    }
    psum += __shfl_xor(psum, 16, 64);
    psum += __shfl_xor(psum, 32, 64);
    lrow += psum;

    // O += P·V  (A = P rows [wave-private], B = V^T)
#pragma unroll
    for (int ks2 = 0; ks2 < 2; ++ks2) {
      bf16x8 ap = *(const bf16x8*)&Ps[(wave * 16 + l15) * 72 + ks2 * 32 + g * 8];
#pragma unroll
      for (int dt = 0; dt < 8; ++dt) {
        int row = dt * 16 + l15;
        bf16x8 bv = *(const bf16x8*)&Vc[row * 64 + (((ks2 * 4 + g) ^ (row & 7)) * 8)];
        oacc[dt] = mfma16(ap, bv, oacc[dt]);
      }
    }
  }
  writeO(tB);
}

// ---------------------------------------------------------------------------
// Output projection, split-K=2: z=0 -> partial p0 (fp32), z=1 -> out (fp32).
// ---------------------------------------------------------------------------
__global__ __launch_bounds__(256) void gemm_proj(const ushort_t* __restrict__ A,
                                                 const ushort_t* __restrict__ B,
                                                 float* __restrict__ C0,
                                                 float* __restrict__ C1) {
  constexpr int KH = 1024, LDK = CDIM, N = HDIM;
  __shared__ __align__(16) ushort_t As[128 * 32];
  __shared__ __align__(16) ushort_t Bs[128 * 32];
  const int z = blockIdx.z;
  const ushort_t* Ap = A + (long)z * KH;
  const ushort_t* Bp = B + (long)z * KH;
  float* Cp = z ? C1 : C0;
  const int m0 = blockIdx.y * 128, n0 = blockIdx.x * 128;
  const int tid = threadIdx.x, lane = tid & 63, wave = tid >> 6;
  const int wm = wave >> 1, wn = wave & 1;
  const int g = lane >> 4, l15 = lane & 15;
  const int srow = tid >> 2, scc = tid & 3;

  f32x4 acc[4][4];
#pragma unroll
  for (int i = 0; i < 4; ++i)
#pragma unroll
    for (int j = 0; j < 4; ++j) acc[i][j] = (f32x4)0.0f;

  for (int k0 = 0; k0 < KH; k0 += 32) {
    __syncthreads();
    {
      int r0 = srow, r1 = srow + 64;
      int c0 = scc ^ ((r0 >> 1) & 3), c1 = scc ^ ((r1 >> 1) & 3);
      async_ld16(&Ap[(long)(m0 + r0) * LDK + k0 + c0 * 8], &As[wave * 512]);
      async_ld16(&Ap[(long)(m0 + r1) * LDK + k0 + c1 * 8], &As[2048 + wave * 512]);
      async_ld16(&Bp[(long)(n0 + r0) * LDK + k0 + c0 * 8], &Bs[wave * 512]);
      async_ld16(&Bp[(long)(n0 + r1) * LDK + k0 + c1 * 8], &Bs[2048 + wave * 512]);
    }
    __syncthreads();

    bf16x8 af[4], bfr[4];
#pragma unroll
    for (int mi = 0; mi < 4; ++mi) {
      int row = wm * 64 + mi * 16 + l15;
      int cc = g ^ ((row >> 1) & 3);
      af[mi] = *(const bf16x8*)&As[row * 32 + cc * 8];
    }
#pragma unroll
    for (int ni = 0; ni < 4; ++ni) {
      int row = wn * 64 + ni * 16 + l15;
      int cc = g ^ ((row >> 1) & 3);
      bfr[ni] = *(const bf16x8*)&Bs[row * 32 + cc * 8];
    }
#pragma unroll
    for (int mi = 0; mi < 4; ++mi)
#pragma unroll
      for (int ni = 0; ni < 4; ++ni)
        acc[mi][ni] = mfma16(af[mi], bfr[ni], acc[mi][ni]);
  }

#pragma unroll
  for (int mi = 0; mi < 4; ++mi)
#pragma unroll
    for (int ni = 0; ni < 4; ++ni) {
      int row = m0 + wm * 64 + mi * 16 + g * 4;
      int col = n0 + wn * 64 + ni * 16 + l15;
#pragma unroll
      for (int r = 0; r < 4; ++r)
        Cp[(long)(row + r) * N + col] = acc[mi][ni][r];
    }
}

__global__ __launch_bounds__(256) void add_out(float* __restrict__ out,
                                               const float* __restrict__ p0, int n4) {
  int i = blockIdx.x * 256 + threadIdx.x;
  if (i >= n4) return;
  float4 a = ((const float4*)out)[i];
  float4 b = ((const float4*)p0)[i];
  a.x += b.x; a.y += b.y; a.z += b.z; a.w += b.w;
  ((float4*)out)[i] = a;
}

// ---------------------------------------------------------------------------
extern "C" void kernel_launch(void* const* d_in, const int* in_sizes, int n_in,
                              void* d_out, int out_size, void* d_ws, size_t ws_size,
                              hipStream_t stream) {
  const float* x       = (const float*)d_in[0];  // (1, 2048, 2048)
  const float* w       = (const float*)d_in[1];  // (4, 2048, 2048)
  const float* ve      = (const float*)d_in[2];  // (1, 2048, 2048)
  const float* lambdas = (const float*)d_in[3];  // (2,)
  float* out = (float*)d_out;

  // ws layout (75.5 MB): qkvb 25.2M | xb 8.4M (=yb) | wb 33.6M | vbT 8.4M
  char* ws = (char*)d_ws;
  ushort_t* qkvb = (ushort_t*)ws;                 // [3][SEQ][HDIM] bf16
  ushort_t* xb   = (ushort_t*)(ws + 25165824);    // [SEQ][CDIM]    bf16
  ushort_t* wb   = (ushort_t*)(ws + 33554432);    // [4][HDIM][CDIM] bf16
  ushort_t* vbT  = (ushort_t*)(ws + 67108864);    // [NH][DH][SEQ]  bf16
  ushort_t* yb   = xb;                            // xb dead after QKV GEMM
  float*    p0   = (float*)ws;                    // qkvb dead after flash

  to_bf16<<<2048, 256, 0, stream>>>(x, xb, (SEQ * CDIM) / 8);
  to_bf16<<<8192, 256, 0, stream>>>(w, wb, (4 * HDIM * CDIM) / 8);
  gemm_qkv<<<dim3(16, 16, 3), 256, 0, stream>>>(xb, wb, qkvb, vbT, ve, lambdas);
  flash_mfma<<<dim3(16, 16), 256, 0, stream>>>(qkvb, vbT, yb);
  gemm_proj<<<dim3(16, 16, 2), 256, 0, stream>>>(yb, wb + 3L * HDIM * CDIM, p0, out);
  add_out<<<4096, 256, 0, stream>>>(out, p0, (SEQ * HDIM) / 4);
}

// Round 5
// 374.215 us; speedup vs baseline: 1.8221x; 1.8221x over previous
//
#include <hip/hip_runtime.h>
#include <math.h>

#define SEQ  2048
#define CDIM 2048
#define NH   16
#define DH   128
#define HDIM 2048   // NH * DH

typedef __attribute__((ext_vector_type(8))) short  bf16x8;  // 8 bf16 = 4 VGPRs
typedef __attribute__((ext_vector_type(4))) float  f32x4;   // MFMA acc
typedef unsigned short ushort_t;

__device__ __forceinline__ unsigned short f2bf(float f) {   // RNE float->bf16
  unsigned u = __float_as_uint(f);
  u = (u + 0x7fffu + ((u >> 16) & 1u)) >> 16;
  return (unsigned short)u;
}
__device__ __forceinline__ float b2f(unsigned short s) {
  return __uint_as_float((unsigned)s << 16);
}

// async global->LDS, 16B per lane. LDS dest is wave-uniform base + lane*16.
__device__ __forceinline__ void async_ld16(const ushort_t* g, ushort_t* l) {
  __builtin_amdgcn_global_load_lds((const __attribute__((address_space(1))) unsigned int*)g,
                                   (__attribute__((address_space(3))) unsigned int*)l,
                                   16, 0, 0);
}

__device__ __forceinline__ f32x4 mfma16(bf16x8 a, bf16x8 b, f32x4 c) {
  return __builtin_amdgcn_mfma_f32_16x16x32_bf16(a, b, c, 0, 0, 0);
}

// ---------------------------------------------------------------------------
// Full-precision RoPE tables (libcalls OK here — no accumulator pressure).
// cosT/sinT: [t][d<32], 2048*32 floats each. Matches jnp fp32 reference.
// ---------------------------------------------------------------------------
__global__ __launch_bounds__(256) void rope_tables(float* __restrict__ cosT,
                                                   float* __restrict__ sinT) {
  int idx = blockIdx.x * 256 + threadIdx.x;   // t*32 + d, 65536 total
  int t = idx >> 5, d = idx & 31;
  float freq = powf(1.0f / 1024.0f, (float)d * (1.0f / 31.0f));
  float th = (float)t * freq;
  cosT[idx] = cosf(th);
  sinT[idx] = sinf(th);
}

// ---------------------------------------------------------------------------
// fp32 -> bf16 pack, 8 elems/thread
// ---------------------------------------------------------------------------
__global__ __launch_bounds__(256) void to_bf16(const float* __restrict__ src,
                                               ushort_t* __restrict__ dst, int n8) {
  int i = blockIdx.x * 256 + threadIdx.x;
  if (i >= n8) return;
  const float4* s = (const float4*)src;
  float4 f0 = s[i * 2], f1 = s[i * 2 + 1];
  bf16x8 o;
  o[0] = (short)f2bf(f0.x); o[1] = (short)f2bf(f0.y);
  o[2] = (short)f2bf(f0.z); o[3] = (short)f2bf(f0.w);
  o[4] = (short)f2bf(f1.x); o[5] = (short)f2bf(f1.y);
  o[6] = (short)f2bf(f1.z); o[7] = (short)f2bf(f1.w);
  *(bf16x8*)&dst[i * 8] = o;
}

// ---------------------------------------------------------------------------
// QKV GEMM (NT) + fused epilogue: rmsnorm + rope (z<2) / v-mix + V-transpose
// (z==2). C-tile = 128 t-rows x 1 head (n-tile 128 == DH). Col remap puts
// rope pairs (c, c+64) in the same lane: col(ni) = (ni&1)*16+wn*32+(ni>>1)*64.
// NOTE: epilogue must contain NO libm calls (powf/cosf) — OCML libcalls force
// accumulator spill to scratch (R3: WRITE_SIZE 2.7 GB, VGPR_Count 68). And
// fast-math __cosf/__sinf are NOT accurate enough at theta~2000 rad (R4 fail).
// -> cos/sin come from precomputed full-precision tables (pure loads).
// ---------------------------------------------------------------------------
__global__ __launch_bounds__(256) void gemm_qkv(const ushort_t* __restrict__ A,
                                                const ushort_t* __restrict__ B,
                                                ushort_t* __restrict__ qkvb,
                                                ushort_t* __restrict__ vbT,
                                                const float* __restrict__ ve,
                                                const float* __restrict__ lambdas,
                                                const float* __restrict__ cosT,
                                                const float* __restrict__ sinT) {
  constexpr int K = CDIM;
  __shared__ __align__(16) ushort_t As[128 * 32];
  __shared__ __align__(16) ushort_t Bs[128 * 32];
  __shared__ float red[4][4][4][4];   // [wave][mi][g][r]
  const int z = blockIdx.z;
  const ushort_t* Bp = B + (long)z * HDIM * CDIM;
  const int m0 = blockIdx.y * 128, n0 = blockIdx.x * 128;
  const int tid = threadIdx.x, lane = tid & 63, wave = tid >> 6;
  const int wm = wave >> 1, wn = wave & 1;
  const int g = lane >> 4, l15 = lane & 15;
  const int srow = tid >> 2, scc = tid & 3;

  f32x4 acc[4][4];
#pragma unroll
  for (int i = 0; i < 4; ++i)
#pragma unroll
    for (int j = 0; j < 4; ++j) acc[i][j] = (f32x4)0.0f;

  for (int k0 = 0; k0 < K; k0 += 32) {
    __syncthreads();
    {
      int r0 = srow, r1 = srow + 64;
      int c0 = scc ^ ((r0 >> 1) & 3), c1 = scc ^ ((r1 >> 1) & 3);
      async_ld16(&A [(long)(m0 + r0) * K + k0 + c0 * 8], &As[wave * 512]);
      async_ld16(&A [(long)(m0 + r1) * K + k0 + c1 * 8], &As[2048 + wave * 512]);
      async_ld16(&Bp[(long)(n0 + r0) * K + k0 + c0 * 8], &Bs[wave * 512]);
      async_ld16(&Bp[(long)(n0 + r1) * K + k0 + c1 * 8], &Bs[2048 + wave * 512]);
    }
    __syncthreads();

    bf16x8 af[4], bfr[4];
#pragma unroll
    for (int mi = 0; mi < 4; ++mi) {
      int row = wm * 64 + mi * 16 + l15;
      int cc = g ^ ((row >> 1) & 3);
      af[mi] = *(const bf16x8*)&As[row * 32 + cc * 8];
    }
#pragma unroll
    for (int ni = 0; ni < 4; ++ni) {
      int rowm = (ni & 1) * 16 + wn * 32 + (ni >> 1) * 64 + l15;   // col remap
      int cc = g ^ ((rowm >> 1) & 3);
      bfr[ni] = *(const bf16x8*)&Bs[rowm * 32 + cc * 8];
    }
#pragma unroll
    for (int mi = 0; mi < 4; ++mi)
#pragma unroll
      for (int ni = 0; ni < 4; ++ni)
        acc[mi][ni] = mfma16(af[mi], bfr[ni], acc[mi][ni]);
  }

  // ---- fused epilogue ----
  // rowsumsq over the 128 head-dims: in-lane over ni, shfl over l15, LDS over wn
  {
    float part[4][4];
#pragma unroll
    for (int mi = 0; mi < 4; ++mi)
#pragma unroll
      for (int r = 0; r < 4; ++r) {
        float s = 0.f;
#pragma unroll
        for (int ni = 0; ni < 4; ++ni) { float v = acc[mi][ni][r]; s += v * v; }
        part[mi][r] = s;
      }
#pragma unroll
    for (int mask = 1; mask < 16; mask <<= 1)
#pragma unroll
      for (int mi = 0; mi < 4; ++mi)
#pragma unroll
        for (int r = 0; r < 4; ++r)
          part[mi][r] += __shfl_xor(part[mi][r], mask, 64);
    __syncthreads();
    if (l15 == 0)
#pragma unroll
      for (int mi = 0; mi < 4; ++mi)
#pragma unroll
        for (int r = 0; r < 4; ++r) red[wave][mi][g][r] = part[mi][r];
    __syncthreads();
  }
  float scl[4][4];
#pragma unroll
  for (int mi = 0; mi < 4; ++mi)
#pragma unroll
    for (int r = 0; r < 4; ++r)
      scl[mi][r] = rsqrtf((red[wm * 2][mi][g][r] + red[wm * 2 + 1][mi][g][r]) *
                              (1.0f / 128.0f) + 1e-6f);

  if (z < 2) {
    ushort_t* dst = qkvb + (long)z * SEQ * HDIM;
#pragma unroll
    for (int ni2 = 0; ni2 < 2; ++ni2) {
      int c = ni2 * 16 + wn * 32 + l15;   // 0..63
      const bool rot = (c < 32);
#pragma unroll
      for (int mi = 0; mi < 4; ++mi)
#pragma unroll
        for (int r = 0; r < 4; ++r) {
          int tt = m0 + wm * 64 + mi * 16 + g * 4 + r;
          float co = rot ? cosT[tt * 32 + c] : 1.0f;   // pure loads, no libcall
          float si = rot ? sinT[tt * 32 + c] : 0.0f;
          float x1 = acc[mi][ni2][r] * scl[mi][r];
          float x2 = acc[mi][ni2 + 2][r] * scl[mi][r];
          dst[(long)tt * HDIM + n0 + c]      = f2bf(x1 * co + x2 * si);
          dst[(long)tt * HDIM + n0 + c + 64] = f2bf(-x1 * si + x2 * co);
        }
    }
  } else {
    float l0 = lambdas[0], l1 = lambdas[1];
    ushort_t* dst = qkvb + 2L * SEQ * HDIM;
#pragma unroll
    for (int mi = 0; mi < 4; ++mi)
#pragma unroll
      for (int ni = 0; ni < 4; ++ni) {
        int c = (ni & 1) * 16 + wn * 32 + (ni >> 1) * 64 + l15;
        int t0q = m0 + wm * 64 + mi * 16 + g * 4;
        unsigned short pk[4];
#pragma unroll
        for (int r = 0; r < 4; ++r) {
          int tt = t0q + r;
          float vv = l0 * acc[mi][ni][r] * scl[mi][r] + l1 * ve[(long)tt * HDIM + n0 + c];
          unsigned short b = f2bf(vv);
          dst[(long)tt * HDIM + n0 + c] = b;
          pk[r] = b;
        }
        *(uint2*)&vbT[(long)(n0 + c) * SEQ + t0q] =
            make_uint2((unsigned)pk[0] | ((unsigned)pk[1] << 16),
                       (unsigned)pk[2] | ((unsigned)pk[3] << 16));
      }
  }
}

// ---------------------------------------------------------------------------
// MFMA flash attention, v2.
// Block = 256 thr (4 waves x 16 q-rows), processes paired q-tiles (x, 31-x)
// sequentially: constant 33 key-tile iterations (load-balanced).
// K/V double-buffered in LDS via global_load_lds; prefetch for iter j+1 is
// issued right after the barrier of iter j.
// No online max: rms-normed q,k bound scores to |s|<=15.36, exp<=4.7e6 (fp32-safe).
// ---------------------------------------------------------------------------
__global__ __launch_bounds__(256) void flash_mfma(const ushort_t* __restrict__ qkvb,
                                                  const ushort_t* __restrict__ vbT,
                                                  ushort_t* __restrict__ yb) {
  __shared__ __align__(16) ushort_t Ks[2][64 * 128];
  __shared__ __align__(16) ushort_t Vt[2][128 * 64];
  __shared__ __align__(16) ushort_t Ps[64 * 72];
  const int xp = blockIdx.x, h = blockIdx.y;
  const int tid = threadIdx.x, lane = tid & 63, wave = tid >> 6;
  const int g = lane >> 4, l15 = lane & 15;
  const ushort_t* Kg = qkvb + (long)SEQ * HDIM + (long)h * DH;
  const ushort_t* Vg = vbT + (long)h * DH * SEQ;
  const int tA = xp, tB = 31 - xp;
  const int nA = xp + 1;           // key-tiles in part A; total = nA + (32-xp) = 33

  auto stage = [&](int buf, int s0) {
#pragma unroll
    for (int i = 0; i < 4; ++i) {
      int idx = i * 256 + tid;
      int rk = idx >> 4, ck = (idx & 15) ^ (rk & 7);
      async_ld16(&Kg[(long)(s0 + rk) * HDIM + ck * 8], &Ks[buf][i * 2048 + wave * 512]);
      int rv = idx >> 3, cv = (idx & 7) ^ (rv & 7);
      async_ld16(&Vg[(long)rv * SEQ + s0 + cv * 8], &Vt[buf][i * 2048 + wave * 512]);
    }
  };

  bf16x8 qf[4];
  auto loadQ = [&](int qt) {
#pragma unroll
    for (int ks = 0; ks < 4; ++ks)
      qf[ks] = *(const bf16x8*)
          &qkvb[(long)(qt * 64 + wave * 16 + l15) * HDIM + h * DH + ks * 32 + g * 8];
  };

  f32x4 oacc[8];
  float lrow = 0.f;
#pragma unroll
  for (int dt = 0; dt < 8; ++dt) oacc[dt] = (f32x4)0.0f;

  auto writeO = [&](int qt) {
    float linv[4];
#pragma unroll
    for (int r = 0; r < 4; ++r) linv[r] = 1.0f / __shfl(lrow, g * 4 + r, 64);
#pragma unroll
    for (int dt = 0; dt < 8; ++dt) {
      int row = qt * 64 + wave * 16 + g * 4;
      int col = h * DH + dt * 16 + l15;
#pragma unroll
      for (int r = 0; r < 4; ++r)
        yb[(long)(row + r) * HDIM + col] = f2bf(oacc[dt][r] * linv[r]);
    }
  };

  loadQ(tA);
  stage(0, 0);

  for (int j = 0; j < 33; ++j) {
    __syncthreads();                       // drains buf[j&1] loads (vmcnt 0 + barrier)
    int part = (j >= nA);
    int qt = part ? tB : tA;
    int s0 = (part ? (j - nA) : j) * 64;
    if (j == nA) {                         // part boundary: flush part A
      writeO(tA);
#pragma unroll
      for (int dt = 0; dt < 8; ++dt) oacc[dt] = (f32x4)0.0f;
      lrow = 0.f;
      loadQ(tB);
    }
    if (j + 1 < 33) {                      // prefetch next tile into other buffer
      int p2 = (j + 1 >= nA);
      int s2 = ((j + 1) - (p2 ? nA : 0)) * 64;
      stage((j + 1) & 1, s2);
    }
    const ushort_t* Kc = Ks[j & 1];
    const ushort_t* Vc = Vt[j & 1];

    // S^T = K·Q^T : C-layout lane: q = l15 (col), key = g*4+reg (row)
    f32x4 st[4];
#pragma unroll
    for (int mt = 0; mt < 4; ++mt) st[mt] = (f32x4)0.0f;
#pragma unroll
    for (int ks = 0; ks < 4; ++ks)
#pragma unroll
      for (int mt = 0; mt < 4; ++mt) {
        int row = mt * 16 + l15;
        bf16x8 a = *(const bf16x8*)&Kc[row * 128 + (((ks * 4 + g) ^ (row & 7)) * 8)];
        st[mt] = mfma16(a, qf[ks], st[mt]);
      }

    // P = exp(0.12*S) (masked -> 0), write to wave-private Ps, accumulate l
    const int qg = qt * 64 + wave * 16 + l15;
    const bool diag = (s0 == qt * 64);
    float psum = 0.f;
#pragma unroll
    for (int mt = 0; mt < 4; ++mt) {
      unsigned short pb[4];
#pragma unroll
      for (int r = 0; r < 4; ++r) {
        float e = (diag && (s0 + mt * 16 + g * 4 + r > qg))
                      ? 0.0f : __expf(st[mt][r] * 0.12f);
        unsigned short b = f2bf(e);
        pb[r] = b;
        psum += b2f(b);                   // l consistent with bf16-rounded P
      }
      *(uint2*)&Ps[(wave * 16 + l15) * 72 + mt * 16 + g * 4] =
          make_uint2((unsigned)pb[0] | ((unsigned)pb[1] << 16),
                     (unsigned)pb[2] | ((unsigned)pb[3] << 16));
    }
    psum += __shfl_xor(psum, 16, 64);
    psum += __shfl_xor(psum, 32, 64);
    lrow += psum;

    // O += P·V  (A = P rows [wave-private], B = V^T)
#pragma unroll
    for (int ks2 = 0; ks2 < 2; ++ks2) {
      bf16x8 ap = *(const bf16x8*)&Ps[(wave * 16 + l15) * 72 + ks2 * 32 + g * 8];
#pragma unroll
      for (int dt = 0; dt < 8; ++dt) {
        int row = dt * 16 + l15;
        bf16x8 bv = *(const bf16x8*)&Vc[row * 64 + (((ks2 * 4 + g) ^ (row & 7)) * 8)];
        oacc[dt] = mfma16(ap, bv, oacc[dt]);
      }
    }
  }
  writeO(tB);
}

// ---------------------------------------------------------------------------
// Output projection, split-K=2: z=0 -> partial p0 (fp32), z=1 -> out (fp32).
// ---------------------------------------------------------------------------
__global__ __launch_bounds__(256) void gemm_proj(const ushort_t* __restrict__ A,
                                                 const ushort_t* __restrict__ B,
                                                 float* __restrict__ C0,
                                                 float* __restrict__ C1) {
  constexpr int KH = 1024, LDK = CDIM, N = HDIM;
  __shared__ __align__(16) ushort_t As[128 * 32];
  __shared__ __align__(16) ushort_t Bs[128 * 32];
  const int z = blockIdx.z;
  const ushort_t* Ap = A + (long)z * KH;
  const ushort_t* Bp = B + (long)z * KH;
  float* Cp = z ? C1 : C0;
  const int m0 = blockIdx.y * 128, n0 = blockIdx.x * 128;
  const int tid = threadIdx.x, lane = tid & 63, wave = tid >> 6;
  const int wm = wave >> 1, wn = wave & 1;
  const int g = lane >> 4, l15 = lane & 15;
  const int srow = tid >> 2, scc = tid & 3;

  f32x4 acc[4][4];
#pragma unroll
  for (int i = 0; i < 4; ++i)
#pragma unroll
    for (int j = 0; j < 4; ++j) acc[i][j] = (f32x4)0.0f;

  for (int k0 = 0; k0 < KH; k0 += 32) {
    __syncthreads();
    {
      int r0 = srow, r1 = srow + 64;
      int c0 = scc ^ ((r0 >> 1) & 3), c1 = scc ^ ((r1 >> 1) & 3);
      async_ld16(&Ap[(long)(m0 + r0) * LDK + k0 + c0 * 8], &As[wave * 512]);
      async_ld16(&Ap[(long)(m0 + r1) * LDK + k0 + c1 * 8], &As[2048 + wave * 512]);
      async_ld16(&Bp[(long)(n0 + r0) * LDK + k0 + c0 * 8], &Bs[wave * 512]);
      async_ld16(&Bp[(long)(n0 + r1) * LDK + k0 + c1 * 8], &Bs[2048 + wave * 512]);
    }
    __syncthreads();

    bf16x8 af[4], bfr[4];
#pragma unroll
    for (int mi = 0; mi < 4; ++mi) {
      int row = wm * 64 + mi * 16 + l15;
      int cc = g ^ ((row >> 1) & 3);
      af[mi] = *(const bf16x8*)&As[row * 32 + cc * 8];
    }
#pragma unroll
    for (int ni = 0; ni < 4; ++ni) {
      int row = wn * 64 + ni * 16 + l15;
      int cc = g ^ ((row >> 1) & 3);
      bfr[ni] = *(const bf16x8*)&Bs[row * 32 + cc * 8];
    }
#pragma unroll
    for (int mi = 0; mi < 4; ++mi)
#pragma unroll
      for (int ni = 0; ni < 4; ++ni)
        acc[mi][ni] = mfma16(af[mi], bfr[ni], acc[mi][ni]);
  }

#pragma unroll
  for (int mi = 0; mi < 4; ++mi)
#pragma unroll
    for (int ni = 0; ni < 4; ++ni) {
      int row = m0 + wm * 64 + mi * 16 + g * 4;
      int col = n0 + wn * 64 + ni * 16 + l15;
#pragma unroll
      for (int r = 0; r < 4; ++r)
        Cp[(long)(row + r) * N + col] = acc[mi][ni][r];
    }
}

__global__ __launch_bounds__(256) void add_out(float* __restrict__ out,
                                               const float* __restrict__ p0, int n4) {
  int i = blockIdx.x * 256 + threadIdx.x;
  if (i >= n4) return;
  float4 a = ((const float4*)out)[i];
  float4 b = ((const float4*)p0)[i];
  a.x += b.x; a.y += b.y; a.z += b.z; a.w += b.w;
  ((float4*)out)[i] = a;
}

// ---------------------------------------------------------------------------
extern "C" void kernel_launch(void* const* d_in, const int* in_sizes, int n_in,
                              void* d_out, int out_size, void* d_ws, size_t ws_size,
                              hipStream_t stream) {
  const float* x       = (const float*)d_in[0];  // (1, 2048, 2048)
  const float* w       = (const float*)d_in[1];  // (4, 2048, 2048)
  const float* ve      = (const float*)d_in[2];  // (1, 2048, 2048)
  const float* lambdas = (const float*)d_in[3];  // (2,)
  float* out = (float*)d_out;

  // ws layout (75.5 MB): qkvb 25.2M | xb 8.4M (=yb) | wb 33.6M | vbT 8.4M
  char* ws = (char*)d_ws;
  ushort_t* qkvb = (ushort_t*)ws;                 // [3][SEQ][HDIM] bf16
  ushort_t* xb   = (ushort_t*)(ws + 25165824);    // [SEQ][CDIM]    bf16
  ushort_t* wb   = (ushort_t*)(ws + 33554432);    // [4][HDIM][CDIM] bf16
  ushort_t* vbT  = (ushort_t*)(ws + 67108864);    // [NH][DH][SEQ]  bf16
  ushort_t* yb   = xb;                            // xb dead after QKV GEMM
  float*    p0   = (float*)ws;                    // qkvb dead after flash

  // RoPE tables scratch: live in d_out (16.8 MB fp32); consumed by gemm_qkv,
  // then gemm_proj overwrites all of out. cosT/sinT = 2048*32 floats each.
  float* cosT = out;
  float* sinT = out + SEQ * 32;

  rope_tables<<<256, 256, 0, stream>>>(cosT, sinT);
  to_bf16<<<2048, 256, 0, stream>>>(x, xb, (SEQ * CDIM) / 8);
  to_bf16<<<8192, 256, 0, stream>>>(w, wb, (4 * HDIM * CDIM) / 8);
  gemm_qkv<<<dim3(16, 16, 3), 256, 0, stream>>>(xb, wb, qkvb, vbT, ve, lambdas,
                                                cosT, sinT);
  flash_mfma<<<dim3(16, 16), 256, 0, stream>>>(qkvb, vbT, yb);
  gemm_proj<<<dim3(16, 16, 2), 256, 0, stream>>>(yb, wb + 3L * HDIM * CDIM, p0, out);
  add_out<<<4096, 256, 0, stream>>>(out, p0, (SEQ * HDIM) / 4);
}

// Round 6
// 370.679 us; speedup vs baseline: 1.8395x; 1.0095x over previous
//
#include <hip/hip_runtime.h>
#include <math.h>

#define SEQ  2048
#define CDIM 2048
#define NH   16
#define DH   128
#define HDIM 2048   // NH * DH

typedef __attribute__((ext_vector_type(8))) short  bf16x8;  // 8 bf16 = 4 VGPRs
typedef __attribute__((ext_vector_type(4))) float  f32x4;   // MFMA acc
typedef unsigned short ushort_t;

__device__ __forceinline__ unsigned short f2bf(float f) {   // RNE float->bf16
  unsigned u = __float_as_uint(f);
  u = (u + 0x7fffu + ((u >> 16) & 1u)) >> 16;
  return (unsigned short)u;
}
__device__ __forceinline__ float b2f(unsigned short s) {
  return __uint_as_float((unsigned)s << 16);
}

// async global->LDS, 16B per lane. LDS dest is wave-uniform base + lane*16.
__device__ __forceinline__ void async_ld16(const ushort_t* g, ushort_t* l) {
  __builtin_amdgcn_global_load_lds((const __attribute__((address_space(1))) unsigned int*)g,
                                   (__attribute__((address_space(3))) unsigned int*)l,
                                   16, 0, 0);
}

__device__ __forceinline__ f32x4 mfma16(bf16x8 a, bf16x8 b, f32x4 c) {
  return __builtin_amdgcn_mfma_f32_16x16x32_bf16(a, b, c, 0, 0, 0);
}

// ---------------------------------------------------------------------------
// Full-precision RoPE tables (libcalls OK here — no accumulator pressure).
// ---------------------------------------------------------------------------
__global__ __launch_bounds__(256) void rope_tables(float* __restrict__ cosT,
                                                   float* __restrict__ sinT) {
  int idx = blockIdx.x * 256 + threadIdx.x;   // t*32 + d, 65536 total
  int t = idx >> 5, d = idx & 31;
  float freq = powf(1.0f / 1024.0f, (float)d * (1.0f / 31.0f));
  float th = (float)t * freq;
  cosT[idx] = cosf(th);
  sinT[idx] = sinf(th);
}

// ---------------------------------------------------------------------------
// fp32 -> bf16 pack, 8 elems/thread
// ---------------------------------------------------------------------------
__global__ __launch_bounds__(256) void to_bf16(const float* __restrict__ src,
                                               ushort_t* __restrict__ dst, int n8) {
  int i = blockIdx.x * 256 + threadIdx.x;
  if (i >= n8) return;
  const float4* s = (const float4*)src;
  float4 f0 = s[i * 2], f1 = s[i * 2 + 1];
  bf16x8 o;
  o[0] = (short)f2bf(f0.x); o[1] = (short)f2bf(f0.y);
  o[2] = (short)f2bf(f0.z); o[3] = (short)f2bf(f0.w);
  o[4] = (short)f2bf(f1.x); o[5] = (short)f2bf(f1.y);
  o[6] = (short)f2bf(f1.z); o[7] = (short)f2bf(f1.w);
  *(bf16x8*)&dst[i * 8] = o;
}

// ---------------------------------------------------------------------------
// QKV GEMM (NT) + fused epilogue. Double-buffered LDS staging (R6): one
// barrier per K-iter, prefetch tile k+1 issued right after the barrier for
// tile k -> the vmcnt(0)-before-s_barrier drain lands loads issued a full
// compute phase earlier (R5: single-buffer drain cost ~40% of the kernel).
// Epilogue: NO libcalls (R3 spill), NO fast-trig (R4 accuracy) — table loads.
// ---------------------------------------------------------------------------
__global__ __launch_bounds__(256) void gemm_qkv(const ushort_t* __restrict__ A,
                                                const ushort_t* __restrict__ B,
                                                ushort_t* __restrict__ qkvb,
                                                ushort_t* __restrict__ vbT,
                                                const float* __restrict__ ve,
                                                const float* __restrict__ lambdas,
                                                const float* __restrict__ cosT,
                                                const float* __restrict__ sinT) {
  constexpr int K = CDIM;
  __shared__ __align__(16) ushort_t As[2][128 * 32];
  __shared__ __align__(16) ushort_t Bs[2][128 * 32];
  __shared__ float red[4][4][4][4];   // [wave][mi][g][r]
  const int z = blockIdx.z;
  const ushort_t* Bp = B + (long)z * HDIM * CDIM;
  const int m0 = blockIdx.y * 128, n0 = blockIdx.x * 128;
  const int tid = threadIdx.x, lane = tid & 63, wave = tid >> 6;
  const int wm = wave >> 1, wn = wave & 1;
  const int g = lane >> 4, l15 = lane & 15;
  const int srow = tid >> 2, scc = tid & 3;

  auto stageG = [&](int buf, int k0) {
    int r0 = srow, r1 = srow + 64;
    int c0 = scc ^ ((r0 >> 1) & 3), c1 = scc ^ ((r1 >> 1) & 3);
    async_ld16(&A [(long)(m0 + r0) * K + k0 + c0 * 8], &As[buf][wave * 512]);
    async_ld16(&A [(long)(m0 + r1) * K + k0 + c1 * 8], &As[buf][2048 + wave * 512]);
    async_ld16(&Bp[(long)(n0 + r0) * K + k0 + c0 * 8], &Bs[buf][wave * 512]);
    async_ld16(&Bp[(long)(n0 + r1) * K + k0 + c1 * 8], &Bs[buf][2048 + wave * 512]);
  };

  f32x4 acc[4][4];
#pragma unroll
  for (int i = 0; i < 4; ++i)
#pragma unroll
    for (int j = 0; j < 4; ++j) acc[i][j] = (f32x4)0.0f;

  stageG(0, 0);
  for (int k0 = 0; k0 < K; k0 += 32) {
    const int buf = (k0 >> 5) & 1;
    __syncthreads();                       // drains buf's loads (issued prev iter)
    if (k0 + 32 < K) stageG(buf ^ 1, k0 + 32);

    bf16x8 af[4], bfr[4];
#pragma unroll
    for (int mi = 0; mi < 4; ++mi) {
      int row = wm * 64 + mi * 16 + l15;
      int cc = g ^ ((row >> 1) & 3);
      af[mi] = *(const bf16x8*)&As[buf][row * 32 + cc * 8];
    }
#pragma unroll
    for (int ni = 0; ni < 4; ++ni) {
      int rowm = (ni & 1) * 16 + wn * 32 + (ni >> 1) * 64 + l15;   // col remap
      int cc = g ^ ((rowm >> 1) & 3);
      bfr[ni] = *(const bf16x8*)&Bs[buf][rowm * 32 + cc * 8];
    }
#pragma unroll
    for (int mi = 0; mi < 4; ++mi)
#pragma unroll
      for (int ni = 0; ni < 4; ++ni)
        acc[mi][ni] = mfma16(af[mi], bfr[ni], acc[mi][ni]);
  }

  // ---- fused epilogue ----
  {
    float part[4][4];
#pragma unroll
    for (int mi = 0; mi < 4; ++mi)
#pragma unroll
      for (int r = 0; r < 4; ++r) {
        float s = 0.f;
#pragma unroll
        for (int ni = 0; ni < 4; ++ni) { float v = acc[mi][ni][r]; s += v * v; }
        part[mi][r] = s;
      }
#pragma unroll
    for (int mask = 1; mask < 16; mask <<= 1)
#pragma unroll
      for (int mi = 0; mi < 4; ++mi)
#pragma unroll
        for (int r = 0; r < 4; ++r)
          part[mi][r] += __shfl_xor(part[mi][r], mask, 64);
    __syncthreads();
    if (l15 == 0)
#pragma unroll
      for (int mi = 0; mi < 4; ++mi)
#pragma unroll
        for (int r = 0; r < 4; ++r) red[wave][mi][g][r] = part[mi][r];
    __syncthreads();
  }
  float scl[4][4];
#pragma unroll
  for (int mi = 0; mi < 4; ++mi)
#pragma unroll
    for (int r = 0; r < 4; ++r)
      scl[mi][r] = rsqrtf((red[wm * 2][mi][g][r] + red[wm * 2 + 1][mi][g][r]) *
                              (1.0f / 128.0f) + 1e-6f);

  if (z < 2) {
    ushort_t* dst = qkvb + (long)z * SEQ * HDIM;
#pragma unroll
    for (int ni2 = 0; ni2 < 2; ++ni2) {
      int c = ni2 * 16 + wn * 32 + l15;   // 0..63
      const bool rot = (c < 32);
#pragma unroll
      for (int mi = 0; mi < 4; ++mi)
#pragma unroll
        for (int r = 0; r < 4; ++r) {
          int tt = m0 + wm * 64 + mi * 16 + g * 4 + r;
          float co = rot ? cosT[tt * 32 + c] : 1.0f;   // pure loads, no libcall
          float si = rot ? sinT[tt * 32 + c] : 0.0f;
          float x1 = acc[mi][ni2][r] * scl[mi][r];
          float x2 = acc[mi][ni2 + 2][r] * scl[mi][r];
          dst[(long)tt * HDIM + n0 + c]      = f2bf(x1 * co + x2 * si);
          dst[(long)tt * HDIM + n0 + c + 64] = f2bf(-x1 * si + x2 * co);
        }
    }
  } else {
    float l0 = lambdas[0], l1 = lambdas[1];
    ushort_t* dst = qkvb + 2L * SEQ * HDIM;
#pragma unroll
    for (int mi = 0; mi < 4; ++mi)
#pragma unroll
      for (int ni = 0; ni < 4; ++ni) {
        int c = (ni & 1) * 16 + wn * 32 + (ni >> 1) * 64 + l15;
        int t0q = m0 + wm * 64 + mi * 16 + g * 4;
        unsigned short pk[4];
#pragma unroll
        for (int r = 0; r < 4; ++r) {
          int tt = t0q + r;
          float vv = l0 * acc[mi][ni][r] * scl[mi][r] + l1 * ve[(long)tt * HDIM + n0 + c];
          unsigned short b = f2bf(vv);
          dst[(long)tt * HDIM + n0 + c] = b;
          pk[r] = b;
        }
        *(uint2*)&vbT[(long)(n0 + c) * SEQ + t0q] =
            make_uint2((unsigned)pk[0] | ((unsigned)pk[1] << 16),
                       (unsigned)pk[2] | ((unsigned)pk[3] << 16));
      }
  }
}

// ---------------------------------------------------------------------------
// MFMA flash attention, v2 (unchanged from R5 — paired q-tiles, dbuf K/V).
// ---------------------------------------------------------------------------
__global__ __launch_bounds__(256) void flash_mfma(const ushort_t* __restrict__ qkvb,
                                                  const ushort_t* __restrict__ vbT,
                                                  ushort_t* __restrict__ yb) {
  __shared__ __align__(16) ushort_t Ks[2][64 * 128];
  __shared__ __align__(16) ushort_t Vt[2][128 * 64];
  __shared__ __align__(16) ushort_t Ps[64 * 72];
  const int xp = blockIdx.x, h = blockIdx.y;
  const int tid = threadIdx.x, lane = tid & 63, wave = tid >> 6;
  const int g = lane >> 4, l15 = lane & 15;
  const ushort_t* Kg = qkvb + (long)SEQ * HDIM + (long)h * DH;
  const ushort_t* Vg = vbT + (long)h * DH * SEQ;
  const int tA = xp, tB = 31 - xp;
  const int nA = xp + 1;           // key-tiles in part A; total = nA + (32-xp) = 33

  auto stage = [&](int buf, int s0) {
#pragma unroll
    for (int i = 0; i < 4; ++i) {
      int idx = i * 256 + tid;
      int rk = idx >> 4, ck = (idx & 15) ^ (rk & 7);
      async_ld16(&Kg[(long)(s0 + rk) * HDIM + ck * 8], &Ks[buf][i * 2048 + wave * 512]);
      int rv = idx >> 3, cv = (idx & 7) ^ (rv & 7);
      async_ld16(&Vg[(long)rv * SEQ + s0 + cv * 8], &Vt[buf][i * 2048 + wave * 512]);
    }
  };

  bf16x8 qf[4];
  auto loadQ = [&](int qt) {
#pragma unroll
    for (int ks = 0; ks < 4; ++ks)
      qf[ks] = *(const bf16x8*)
          &qkvb[(long)(qt * 64 + wave * 16 + l15) * HDIM + h * DH + ks * 32 + g * 8];
  };

  f32x4 oacc[8];
  float lrow = 0.f;
#pragma unroll
  for (int dt = 0; dt < 8; ++dt) oacc[dt] = (f32x4)0.0f;

  auto writeO = [&](int qt) {
    float linv[4];
#pragma unroll
    for (int r = 0; r < 4; ++r) linv[r] = 1.0f / __shfl(lrow, g * 4 + r, 64);
#pragma unroll
    for (int dt = 0; dt < 8; ++dt) {
      int row = qt * 64 + wave * 16 + g * 4;
      int col = h * DH + dt * 16 + l15;
#pragma unroll
      for (int r = 0; r < 4; ++r)
        yb[(long)(row + r) * HDIM + col] = f2bf(oacc[dt][r] * linv[r]);
    }
  };

  loadQ(tA);
  stage(0, 0);

  for (int j = 0; j < 33; ++j) {
    __syncthreads();                       // drains buf[j&1] loads
    int part = (j >= nA);
    int qt = part ? tB : tA;
    int s0 = (part ? (j - nA) : j) * 64;
    if (j == nA) {                         // part boundary: flush part A
      writeO(tA);
#pragma unroll
      for (int dt = 0; dt < 8; ++dt) oacc[dt] = (f32x4)0.0f;
      lrow = 0.f;
      loadQ(tB);
    }
    if (j + 1 < 33) {                      // prefetch next tile into other buffer
      int p2 = (j + 1 >= nA);
      int s2 = ((j + 1) - (p2 ? nA : 0)) * 64;
      stage((j + 1) & 1, s2);
    }
    const ushort_t* Kc = Ks[j & 1];
    const ushort_t* Vc = Vt[j & 1];

    // S^T = K·Q^T : C-layout lane: q = l15 (col), key = g*4+reg (row)
    f32x4 st[4];
#pragma unroll
    for (int mt = 0; mt < 4; ++mt) st[mt] = (f32x4)0.0f;
#pragma unroll
    for (int ks = 0; ks < 4; ++ks)
#pragma unroll
      for (int mt = 0; mt < 4; ++mt) {
        int row = mt * 16 + l15;
        bf16x8 a = *(const bf16x8*)&Kc[row * 128 + (((ks * 4 + g) ^ (row & 7)) * 8)];
        st[mt] = mfma16(a, qf[ks], st[mt]);
      }

    // P = exp(0.12*S) (masked -> 0), write to wave-private Ps, accumulate l
    const int qg = qt * 64 + wave * 16 + l15;
    const bool diag = (s0 == qt * 64);
    float psum = 0.f;
#pragma unroll
    for (int mt = 0; mt < 4; ++mt) {
      unsigned short pb[4];
#pragma unroll
      for (int r = 0; r < 4; ++r) {
        float e = (diag && (s0 + mt * 16 + g * 4 + r > qg))
                      ? 0.0f : __expf(st[mt][r] * 0.12f);
        unsigned short b = f2bf(e);
        pb[r] = b;
        psum += b2f(b);                   // l consistent with bf16-rounded P
      }
      *(uint2*)&Ps[(wave * 16 + l15) * 72 + mt * 16 + g * 4] =
          make_uint2((unsigned)pb[0] | ((unsigned)pb[1] << 16),
                     (unsigned)pb[2] | ((unsigned)pb[3] << 16));
    }
    psum += __shfl_xor(psum, 16, 64);
    psum += __shfl_xor(psum, 32, 64);
    lrow += psum;

    // O += P·V  (A = P rows [wave-private], B = V^T)
#pragma unroll
    for (int ks2 = 0; ks2 < 2; ++ks2) {
      bf16x8 ap = *(const bf16x8*)&Ps[(wave * 16 + l15) * 72 + ks2 * 32 + g * 8];
#pragma unroll
      for (int dt = 0; dt < 8; ++dt) {
        int row = dt * 16 + l15;
        bf16x8 bv = *(const bf16x8*)&Vc[row * 64 + (((ks2 * 4 + g) ^ (row & 7)) * 8)];
        oacc[dt] = mfma16(ap, bv, oacc[dt]);
      }
    }
  }
  writeO(tB);
}

// ---------------------------------------------------------------------------
// Output projection, split-K=2, double-buffered staging (R6).
// z=0 -> partial p0 (fp32), z=1 -> out (fp32).
// ---------------------------------------------------------------------------
__global__ __launch_bounds__(256) void gemm_proj(const ushort_t* __restrict__ A,
                                                 const ushort_t* __restrict__ B,
                                                 float* __restrict__ C0,
                                                 float* __restrict__ C1) {
  constexpr int KH = 1024, LDK = CDIM, N = HDIM;
  __shared__ __align__(16) ushort_t As[2][128 * 32];
  __shared__ __align__(16) ushort_t Bs[2][128 * 32];
  const int z = blockIdx.z;
  const ushort_t* Ap = A + (long)z * KH;
  const ushort_t* Bp = B + (long)z * KH;
  float* Cp = z ? C1 : C0;
  const int m0 = blockIdx.y * 128, n0 = blockIdx.x * 128;
  const int tid = threadIdx.x, lane = tid & 63, wave = tid >> 6;
  const int wm = wave >> 1, wn = wave & 1;
  const int g = lane >> 4, l15 = lane & 15;
  const int srow = tid >> 2, scc = tid & 3;

  auto stageG = [&](int buf, int k0) {
    int r0 = srow, r1 = srow + 64;
    int c0 = scc ^ ((r0 >> 1) & 3), c1 = scc ^ ((r1 >> 1) & 3);
    async_ld16(&Ap[(long)(m0 + r0) * LDK + k0 + c0 * 8], &As[buf][wave * 512]);
    async_ld16(&Ap[(long)(m0 + r1) * LDK + k0 + c1 * 8], &As[buf][2048 + wave * 512]);
    async_ld16(&Bp[(long)(n0 + r0) * LDK + k0 + c0 * 8], &Bs[buf][wave * 512]);
    async_ld16(&Bp[(long)(n0 + r1) * LDK + k0 + c1 * 8], &Bs[buf][2048 + wave * 512]);
  };

  f32x4 acc[4][4];
#pragma unroll
  for (int i = 0; i < 4; ++i)
#pragma unroll
    for (int j = 0; j < 4; ++j) acc[i][j] = (f32x4)0.0f;

  stageG(0, 0);
  for (int k0 = 0; k0 < KH; k0 += 32) {
    const int buf = (k0 >> 5) & 1;
    __syncthreads();
    if (k0 + 32 < KH) stageG(buf ^ 1, k0 + 32);

    bf16x8 af[4], bfr[4];
#pragma unroll
    for (int mi = 0; mi < 4; ++mi) {
      int row = wm * 64 + mi * 16 + l15;
      int cc = g ^ ((row >> 1) & 3);
      af[mi] = *(const bf16x8*)&As[buf][row * 32 + cc * 8];
    }
#pragma unroll
    for (int ni = 0; ni < 4; ++ni) {
      int row = wn * 64 + ni * 16 + l15;
      int cc = g ^ ((row >> 1) & 3);
      bfr[ni] = *(const bf16x8*)&Bs[buf][row * 32 + cc * 8];
    }
#pragma unroll
    for (int mi = 0; mi < 4; ++mi)
#pragma unroll
      for (int ni = 0; ni < 4; ++ni)
        acc[mi][ni] = mfma16(af[mi], bfr[ni], acc[mi][ni]);
  }

#pragma unroll
  for (int mi = 0; mi < 4; ++mi)
#pragma unroll
    for (int ni = 0; ni < 4; ++ni) {
      int row = m0 + wm * 64 + mi * 16 + g * 4;
      int col = n0 + wn * 64 + ni * 16 + l15;
#pragma unroll
      for (int r = 0; r < 4; ++r)
        Cp[(long)(row + r) * N + col] = acc[mi][ni][r];
    }
}

__global__ __launch_bounds__(256) void add_out(float* __restrict__ out,
                                               const float* __restrict__ p0, int n4) {
  int i = blockIdx.x * 256 + threadIdx.x;
  if (i >= n4) return;
  float4 a = ((const float4*)out)[i];
  float4 b = ((const float4*)p0)[i];
  a.x += b.x; a.y += b.y; a.z += b.z; a.w += b.w;
  ((float4*)out)[i] = a;
}

// ---------------------------------------------------------------------------
extern "C" void kernel_launch(void* const* d_in, const int* in_sizes, int n_in,
                              void* d_out, int out_size, void* d_ws, size_t ws_size,
                              hipStream_t stream) {
  const float* x       = (const float*)d_in[0];  // (1, 2048, 2048)
  const float* w       = (const float*)d_in[1];  // (4, 2048, 2048)
  const float* ve      = (const float*)d_in[2];  // (1, 2048, 2048)
  const float* lambdas = (const float*)d_in[3];  // (2,)
  float* out = (float*)d_out;

  // ws layout (75.5 MB): qkvb 25.2M | xb 8.4M (=yb) | wb 33.6M | vbT 8.4M
  char* ws = (char*)d_ws;
  ushort_t* qkvb = (ushort_t*)ws;                 // [3][SEQ][HDIM] bf16
  ushort_t* xb   = (ushort_t*)(ws + 25165824);    // [SEQ][CDIM]    bf16
  ushort_t* wb   = (ushort_t*)(ws + 33554432);    // [4][HDIM][CDIM] bf16
  ushort_t* vbT  = (ushort_t*)(ws + 67108864);    // [NH][DH][SEQ]  bf16
  ushort_t* yb   = xb;                            // xb dead after QKV GEMM
  float*    p0   = (float*)ws;                    // qkvb dead after flash

  // RoPE tables scratch: live in d_out (16.8 MB fp32); consumed by gemm_qkv,
  // then gemm_proj overwrites all of out. cosT/sinT = 2048*32 floats each.
  float* cosT = out;
  float* sinT = out + SEQ * 32;

  rope_tables<<<256, 256, 0, stream>>>(cosT, sinT);
  to_bf16<<<2048, 256, 0, stream>>>(x, xb, (SEQ * CDIM) / 8);
  to_bf16<<<8192, 256, 0, stream>>>(w, wb, (4 * HDIM * CDIM) / 8);
  gemm_qkv<<<dim3(16, 16, 3), 256, 0, stream>>>(xb, wb, qkvb, vbT, ve, lambdas,
                                                cosT, sinT);
  flash_mfma<<<dim3(16, 16), 256, 0, stream>>>(qkvb, vbT, yb);
  gemm_proj<<<dim3(16, 16, 2), 256, 0, stream>>>(yb, wb + 3L * HDIM * CDIM, p0, out);
  add_out<<<4096, 256, 0, stream>>>(out, p0, (SEQ * HDIM) / 4);
}